// Round 1
// 125.575 us; speedup vs baseline: 1.0103x; 1.0103x over previous
//
#include <hip/hip_runtime.h>

#define NN 64000
#define NG 512
#define NPG 125
#define DIM 128
#define NC 10
#define SHID 69
#define NF 16
#define PHID 8
#define ELPAD 132   // E rows padded 128->132 in LDS (tail)
#define TSTR 81     // Ts row stride (odd -> conflict-free), 128 rows
#define PSTR 21     // Ps row stride (odd -> conflict-free), 2 partials x 10

// output float offsets (concatenated tuple, row-major)
#define OFF_PRED1 0
#define OFF_PRED2 1024
#define OFF_IND   2048
#define OFF_S     2560
#define OFF_E     642560
#define OFF_Q     1297920

typedef __attribute__((ext_vector_type(8))) short short8;   // 8 bf16 (4 VGPRs)
typedef __attribute__((ext_vector_type(4))) float f32x4;    // MFMA C/D

// ---------------- threefry2x32 (JAX-exact, key = (0, 42)) ----------------
__device__ __forceinline__ unsigned rotl32(unsigned x, int r) {
    return (x << r) | (x >> (32 - r));
}

__device__ __forceinline__ void threefry_0_42(unsigned x0, unsigned x1,
                                              unsigned& o0, unsigned& o1) {
    const unsigned k0 = 0u, k1 = 42u;
    const unsigned k2 = k0 ^ k1 ^ 0x1BD11BDAu;
    unsigned ks[3] = {k0, k1, k2};
    const int R0[4] = {13, 15, 26, 6};
    const int R1[4] = {17, 29, 16, 24};
    x0 += k0; x1 += k1;
    #pragma unroll
    for (int i = 0; i < 5; i++) {
        const int* R = (i & 1) ? R1 : R0;
        #pragma unroll
        for (int r = 0; r < 4; r++) {
            x0 += x1;
            x1 = rotl32(x1, R[r]);
            x1 ^= x0;
        }
        x0 += ks[(i + 1) % 3];
        x1 += ks[(i + 2) % 3] + (unsigned)(i + 1);
    }
    o0 = x0; o1 = x1;
}

// jax_threefry_partitionable: element i -> counter (0, i); bits = o0 ^ o1. (verified R2)
__device__ __forceinline__ unsigned random_bits_partitionable(unsigned i) {
    unsigned o0, o1;
    threefry_0_42(0u, i, o0, o1);
    return o0 ^ o1;
}

__device__ __forceinline__ float gumbel_from_bits(unsigned bits) {
    float f = __uint_as_float((bits >> 9) | 0x3f800000u) - 1.0f;  // [0,1)
    if (f <= 0.0f) f = 1.1754943508222875e-38f;                   // minval=tiny
    return -logf(-logf(f));
}

#define R10(M) M(0) M(1) M(2) M(3) M(4) M(5) M(6) M(7) M(8) M(9)

// ---------------- K0: split w1 into bf16 hi/lo B-fragments in workspace ----------------
// Same fragment layout as the previous in-kernel staging: slot = (jt*4+ks)*64 + l,
// element i; value = w1[(ks*32 + ((l>>4)&3)*8 + i) * SHID + (jt*16 + (l&15))], zero-padded
// for j >= 69. wsHi = ws[0..10239], wsLo = ws[10240..20479] (shorts).
__global__ void k_split_w1(const float* __restrict__ w1, short* __restrict__ ws) {
    int e = blockIdx.x * 256 + threadIdx.x;   // 0..10239
    int slot = e >> 3, i = e & 7;
    int jt = slot >> 8, ks = (slot >> 6) & 3, l = slot & 63;
    int j = jt * 16 + (l & 15);
    int kb = ks * 32 + ((l >> 4) & 3) * 8;
    float x = (j < SHID) ? w1[(kb + i) * SHID + j] : 0.0f;
    unsigned u = __float_as_uint(x);
    short hi = (short)(u >> 16);
    float hf = __uint_as_float(u & 0xFFFF0000u);
    short lo = (short)(__float_as_uint(x - hf) >> 16);
    ws[e] = hi;
    ws[10240 + e] = lo;
}

// ---------------- K1: fully fused per-graph kernel ----------------
// Block = 1 graph (125 nodes padded to 128), 256 threads = 4 waves; wave w owns
// m-tiles {2w, 2w+1} (32 nodes). Phases:
//   0) copy pre-split w1 frags from ws -> LDS (40960 B, pure float4 copy)
//   1) node MLP layer 1 via split-bf16 mfma_f32_16x16x32_bf16 (verified layout:
//      A[m=lane&15][k=(lane>>4)*8+i], C/D row=(lane>>4)*4+reg, col=lane&15)
//   2) relu+bias -> Ts[128][TSTR] (aliases frag LDS), layer 2 -> Ps, softmax -> S
//      (global write) + Ss (LDS, rows 125..127 zeroed)
//   3) E = S^T H in-block: H re-read from global (L2-resident: 64 KB/block,
//      512 blocks all co-resident at 2 blocks/CU) -> El (LDS) + E (global)
//   4) verified tail (corr, pred1, gumbel sample, Q, feature_mask, pred2) on wave 0
__global__ __launch_bounds__(256, 2) void k_fused(
    const float* __restrict__ H, const short* __restrict__ ws,
    const float* __restrict__ b1, const float* __restrict__ w2,
    const float* __restrict__ b2,
    const float* __restrict__ wf, const float* __restrict__ bf,
    const int* __restrict__ targets,
    const float* __restrict__ p1, const float* __restrict__ pb1,
    const float* __restrict__ p2, const float* __restrict__ pb2,
    const float* __restrict__ ci, const float* __restrict__ cr,
    float* __restrict__ S, float* __restrict__ E,
    float* __restrict__ pred1, float* __restrict__ pred2,
    float* __restrict__ ind, float* __restrict__ Q) {
    // LDS map (peak 57600 B -> 2 blocks/CU):
    //   phase 1: fragHi @0 (20480), fragLo @20480 (20480)
    //   phase 2: Ts @0 (128*81*4=41472), Ps @41472 (128*21*4=10752), Ss @52224 (5120)
    //   phase 3/4: Epart @0 (5120), El @8192 (5280), fmbuf @16384 (40); Ss stays live
    __shared__ __align__(16) char lds[57600];
    int g = blockIdx.x, tid = threadIdx.x;

    // ---- phase 0: stage pre-split fragments ----
    {
        const float4* src = (const float4*)ws;
        float4* dst = (float4*)lds;
        #pragma unroll
        for (int k = 0; k < 10; k++) dst[k * 256 + tid] = src[k * 256 + tid];
    }
    short* fragHi = (short*)lds;
    short* fragLo = (short*)(lds + 20480);
    __syncthreads();

    int w = tid >> 6, l = tid & 63;

    // ---- A fragments (hi/lo) for 2 m-tiles x 4 k-steps ----
    short8 aHi[2][4], aLo[2][4];
    #pragma unroll
    for (int h = 0; h < 2; h++) {
        int r = (w * 2 + h) * 16 + (l & 15);        // node row within graph
        bool valid = (r < NPG);
        const float* Hp = H + ((size_t)g * NPG + (valid ? r : 0)) * DIM + ((l >> 4) & 3) * 8;
        #pragma unroll
        for (int ks = 0; ks < 4; ks++) {
            float xs[8];
            if (valid) {
                float4 x0 = *(const float4*)(Hp + ks * 32);
                float4 x1 = *(const float4*)(Hp + ks * 32 + 4);
                xs[0] = x0.x; xs[1] = x0.y; xs[2] = x0.z; xs[3] = x0.w;
                xs[4] = x1.x; xs[5] = x1.y; xs[6] = x1.z; xs[7] = x1.w;
            } else {
                #pragma unroll
                for (int i = 0; i < 8; i++) xs[i] = 0.0f;
            }
            #pragma unroll
            for (int i = 0; i < 8; i++) {
                unsigned u = __float_as_uint(xs[i]);
                aHi[h][ks][i] = (short)(u >> 16);
                float lo = xs[i] - __uint_as_float(u & 0xFFFF0000u);
                aLo[h][ks][i] = (short)(__float_as_uint(lo) >> 16);
            }
        }
    }

    // ---- MFMA: 5 j-tiles x 4 k-steps x (hihi, lohi, hilo) x 2 m-tiles ----
    // B frags shared across both m-tiles -> one LDS read pair per (jt,ks).
    f32x4 acc[2][5];
    #pragma unroll
    for (int h = 0; h < 2; h++)
        #pragma unroll
        for (int jt = 0; jt < 5; jt++) acc[h][jt] = (f32x4){0.f, 0.f, 0.f, 0.f};
    #pragma unroll
    for (int jt = 0; jt < 5; jt++) {
        #pragma unroll
        for (int ks = 0; ks < 4; ks++) {
            int slot = (jt * 4 + ks) * 64 + l;
            short8 bh = *(short8*)(fragHi + (size_t)slot * 8);
            short8 bl = *(short8*)(fragLo + (size_t)slot * 8);
            acc[0][jt] = __builtin_amdgcn_mfma_f32_16x16x32_bf16(aHi[0][ks], bh, acc[0][jt], 0, 0, 0);
            acc[1][jt] = __builtin_amdgcn_mfma_f32_16x16x32_bf16(aHi[1][ks], bh, acc[1][jt], 0, 0, 0);
            acc[0][jt] = __builtin_amdgcn_mfma_f32_16x16x32_bf16(aLo[0][ks], bh, acc[0][jt], 0, 0, 0);
            acc[1][jt] = __builtin_amdgcn_mfma_f32_16x16x32_bf16(aLo[1][ks], bh, acc[1][jt], 0, 0, 0);
            acc[0][jt] = __builtin_amdgcn_mfma_f32_16x16x32_bf16(aHi[0][ks], bl, acc[0][jt], 0, 0, 0);
            acc[1][jt] = __builtin_amdgcn_mfma_f32_16x16x32_bf16(aHi[1][ks], bl, acc[1][jt], 0, 0, 0);
        }
    }
    __syncthreads();   // frag reads done -> safe to alias LDS with Ts

    // ---- relu(t + b1) into Ts[128][TSTR] (pad j>=69 -> 0) ----
    float* Ts = (float*)lds;
    #pragma unroll
    for (int jt = 0; jt < 5; jt++) {
        int j = jt * 16 + (l & 15);
        float bj = (j < SHID) ? b1[j] : 0.0f;
        #pragma unroll
        for (int h = 0; h < 2; h++) {
            #pragma unroll
            for (int r = 0; r < 4; r++) {
                int m = (w * 2 + h) * 16 + ((l >> 4) & 3) * 4 + r;
                float tv = acc[h][jt][r];
                Ts[m * TSTR + j] = (j < SHID) ? fmaxf(tv + bj, 0.0f) : 0.0f;
            }
        }
    }
    __syncthreads();

    // ---- layer 2 partials: thread (n = tid&127, q = tid>>7), j in [q*36, q*36+36) ----
    float* Ps = (float*)(lds + 41472);
    {
        int n = tid & 127, q = tid >> 7;
        float lg[NC] = {};
        for (int jj = 0; jj < 36; jj++) {
            int j = q * 36 + jj;               // < 72; Ts is 0 for j >= 69
            int jx = (j < SHID) ? j : (SHID - 1);
            float tr = Ts[n * TSTR + j];
            const float* w2r = w2 + jx * NC;   // wave-uniform -> s_load
            #pragma unroll
            for (int c = 0; c < NC; c++) lg[c] = fmaf(tr, w2r[c], lg[c]);
        }
        #pragma unroll
        for (int c = 0; c < NC; c++) Ps[n * PSTR + q * NC + c] = lg[c];
    }
    __syncthreads();

    // ---- combine + softmax -> S (global) + Ss (LDS); rows 125..127 -> Ss = 0 ----
    float* Ss = (float*)(lds + 52224);
    if (tid < 128) {
        int n = tid;
        if (n < NPG) {
            const float* pr = &Ps[n * PSTR];
            #define LD(c) float s##c = pr[c] + pr[NC + c] + b2[c];
            R10(LD)
            #undef LD
            float m = fmaxf(fmaxf(fmaxf(s0, s1), fmaxf(s2, s3)),
                            fmaxf(fmaxf(fmaxf(s4, s5), fmaxf(s6, s7)), fmaxf(s8, s9)));
            float e0 = expf(s0 - m), e1 = expf(s1 - m), e2 = expf(s2 - m),
                  e3 = expf(s3 - m), e4 = expf(s4 - m), e5 = expf(s5 - m),
                  e6 = expf(s6 - m), e7 = expf(s7 - m), e8 = expf(s8 - m),
                  e9 = expf(s9 - m);
            float ssum = ((e0 + e1) + (e2 + e3)) + ((e4 + e5) + (e6 + e7)) + (e8 + e9);
            float inv = 1.0f / ssum;
            float v0 = e0 * inv, v1 = e1 * inv, v2 = e2 * inv, v3 = e3 * inv,
                  v4 = e4 * inv, v5 = e5 * inv, v6 = e6 * inv, v7 = e7 * inv,
                  v8 = e8 * inv, v9 = e9 * inv;
            float2* Sp2 = (float2*)(S + ((size_t)g * NPG + n) * NC);
            Sp2[0] = make_float2(v0, v1);
            Sp2[1] = make_float2(v2, v3);
            Sp2[2] = make_float2(v4, v5);
            Sp2[3] = make_float2(v6, v7);
            Sp2[4] = make_float2(v8, v9);
            float2* Ss2 = (float2*)(Ss + n * NC);
            Ss2[0] = make_float2(v0, v1);
            Ss2[1] = make_float2(v2, v3);
            Ss2[2] = make_float2(v4, v5);
            Ss2[3] = make_float2(v6, v7);
            Ss2[4] = make_float2(v8, v9);
        } else {
            float2* Ss2 = (float2*)(Ss + n * NC);
            Ss2[0] = make_float2(0.f, 0.f);
            Ss2[1] = make_float2(0.f, 0.f);
            Ss2[2] = make_float2(0.f, 0.f);
            Ss2[3] = make_float2(0.f, 0.f);
            Ss2[4] = make_float2(0.f, 0.f);
        }
    }
    __syncthreads();

    // ---- E = S^T H: thread (q = node-half, d); H re-read (L2-resident) ----
    float* Epart = (float*)lds;            // aliases dead Ts
    float* El    = (float*)(lds + 8192);
    float* fmbuf = (float*)(lds + 16384);
    {
        int q = tid >> 7, d = tid & 127;
        const float* Hg = H + (size_t)g * NPG * DIM + d;
        #define DECLA(c) float a##c = 0.f;
        R10(DECLA)
        #undef DECLA
        int n0 = q * 64;
        #pragma unroll
        for (int ib = 0; ib < 64; ib += 4) {
            float h4[4];
            #pragma unroll
            for (int u = 0; u < 4; u++) {
                int nh = min(n0 + ib + u, NPG - 1);   // rows 125..127 have Ss=0
                h4[u] = Hg[(size_t)nh * DIM];
            }
            #pragma unroll
            for (int u = 0; u < 4; u++) {
                const float2* S2 = (const float2*)(Ss + (n0 + ib + u) * NC);
                float2 s01 = S2[0], s23 = S2[1], s45 = S2[2], s67 = S2[3], s89 = S2[4];
                a0 = fmaf(s01.x, h4[u], a0); a1 = fmaf(s01.y, h4[u], a1);
                a2 = fmaf(s23.x, h4[u], a2); a3 = fmaf(s23.y, h4[u], a3);
                a4 = fmaf(s45.x, h4[u], a4); a5 = fmaf(s45.y, h4[u], a5);
                a6 = fmaf(s67.x, h4[u], a6); a7 = fmaf(s67.y, h4[u], a7);
                a8 = fmaf(s89.x, h4[u], a8); a9 = fmaf(s89.y, h4[u], a9);
            }
        }
        if (q == 1) {
            float* ep = &Epart[d * NC];
            #define STP(c) ep[c] = a##c;
            R10(STP)
            #undef STP
        }
        __syncthreads();
        if (q == 0) {
            const float* ep = &Epart[d * NC];
            float* Eo = E + (size_t)g * (NC * DIM) + d;
            #define CMB(c) { a##c += ep[c]; El[c * ELPAD + d] = a##c; Eo[c * DIM] = a##c; }
            R10(CMB)
            #undef CMB
        }
    }
    __syncthreads();

    // ---- tail (verified): corr, pred1, sample, Q, feature_mask, pred2 ----
    const float2* wf2 = (const float2*)wf;
    int samp = 0;
    float corr_lf = 0.f;

    if (tid < 64) {
        // ---- corr: lane l<32 computes corr[i=l>>4][f=l&15] ----
        if (l < 32) {
            int i = l >> 4, f = l & 15;
            float a = ci[f], b = ci[NF + f];
            float mm = fmaxf(a, b);
            float ea = expf(a - mm), eb = expf(b - mm);
            float inter = expf(ci[i * NF + f] - mm) / (ea + eb);
            float mi = -1e30f;
            for (int j = 0; j < NF; j++) mi = fmaxf(mi, cr[i * NF + j]);
            float ri = 0.f;
            for (int j = 0; j < NF; j++) ri += expf(cr[i * NF + j] - mi);
            float intra = expf(cr[i * NF + f] - mi) / ri;
            corr_lf = inter * intra;
        }

        // ---- phase 1: pred1 + softmax + gumbel sample + ind ----
        float a0 = 0.f, a1 = 0.f;
        #pragma unroll
        for (int i = 0; i < 20; i++) {
            int idx = i * 64 + l;
            float e = El[(idx >> 7) * ELPAD + (idx & 127)];
            float2 wv = wf2[idx];
            a0 = fmaf(e, wv.x, a0);
            a1 = fmaf(e, wv.y, a1);
        }
        #pragma unroll
        for (int off = 32; off > 0; off >>= 1) {
            a0 += __shfl_down(a0, off);
            a1 += __shfl_down(a1, off);
        }
        if (l == 0) {
            float y0 = a0 + bf[0], y1 = a1 + bf[1];
            pred1[g * 2] = y0;
            pred1[g * 2 + 1] = y1;
            float m = fmaxf(y0, y1);
            float e0 = expf(y0 - m), e1 = expf(y1 - m), s = e0 + e1;
            float p0 = e0 / s, pp1 = e1 / s;
            float g0 = gumbel_from_bits(random_bits_partitionable(2 * g));
            float g1 = gumbel_from_bits(random_bits_partitionable(2 * g + 1));
            float l0 = logf(p0 + 1e-12f) + g0;
            float l1 = logf(pp1 + 1e-12f) + g1;
            samp = (l1 > l0) ? 1 : 0;
            ind[g] = (samp == targets[g]) ? 1.0f : 0.0f;
        }
        samp = __shfl(samp, 0);

        // ---- phase 2: Q-MLP (128->8 relu ->16 softmax) + feature_mask ----
        if (l < 40) {
            int p = l >> 2, s = l & 3;
            float ua = pb1[2 * s], ub = pb1[2 * s + 1];
            const float4* E4 = (const float4*)&El[p * ELPAD];
            #pragma unroll 4
            for (int k4 = 0; k4 < 32; k4++) {
                float4 e4 = E4[k4];
                float es[4] = {e4.x, e4.y, e4.z, e4.w};
                #pragma unroll
                for (int kk = 0; kk < 4; kk++) {
                    int k = k4 * 4 + kk;
                    ua = fmaf(es[kk], p1[k * PHID + 2 * s], ua);
                    ub = fmaf(es[kk], p1[k * PHID + 2 * s + 1], ub);
                }
            }
            ua = fmaxf(ua, 0.f);
            ub = fmaxf(ub, 0.f);
            float v[NF];
            #pragma unroll
            for (int f = 0; f < NF; f++) {
                v[f] = pb2[f] * 0.25f;  // bias split: reduce over 4 lanes adds it once
                v[f] = fmaf(ua, p2[(2 * s) * NF + f], v[f]);
                v[f] = fmaf(ub, p2[(2 * s + 1) * NF + f], v[f]);
            }
            #pragma unroll
            for (int f = 0; f < NF; f++) {
                v[f] += __shfl_xor(v[f], 1);
                v[f] += __shfl_xor(v[f], 2);
            }
            float m = v[0];
            #pragma unroll
            for (int f = 1; f < NF; f++) m = fmaxf(m, v[f]);
            float ssum = 0.f, qv[NF];
            #pragma unroll
            for (int f = 0; f < NF; f++) { qv[f] = expf(v[f] - m); ssum += qv[f]; }
            float inv = 1.0f / ssum;
            #pragma unroll
            for (int f = 0; f < NF; f++) qv[f] *= inv;
            float* Qo = Q + ((size_t)g * NC + p) * NF;
            ((float4*)Qo)[s] = make_float4(qv[s * 4], qv[s * 4 + 1], qv[s * 4 + 2], qv[s * 4 + 3]);
            float fmv = 0.f;
            #pragma unroll
            for (int f = 0; f < NF; f++) {
                float cv = __shfl(corr_lf, samp * NF + f);
                fmv = fmaf(qv[f], cv, fmv);
            }
            if (s == 0) fmbuf[p] = fmv;
        }
    }
    __syncthreads();

    if (tid < 64) {
        // ---- phase 3: pred2 ----
        float b0 = 0.f, b1acc = 0.f;
        #pragma unroll
        for (int i = 0; i < 20; i++) {
            int idx = i * 64 + l;
            float e = El[(idx >> 7) * ELPAD + (idx & 127)] * fmbuf[idx >> 7];
            float2 wv = wf2[idx];
            b0 = fmaf(e, wv.x, b0);
            b1acc = fmaf(e, wv.y, b1acc);
        }
        #pragma unroll
        for (int off = 32; off > 0; off >>= 1) {
            b0 += __shfl_down(b0, off);
            b1acc += __shfl_down(b1acc, off);
        }
        if (l == 0) {
            pred2[g * 2] = b0 + bf[0];
            pred2[g * 2 + 1] = b1acc + bf[1];
        }
    }
}

extern "C" void kernel_launch(void* const* d_in, const int* in_sizes, int n_in,
                              void* d_out, int out_size, void* d_ws, size_t ws_size,
                              hipStream_t stream) {
    const float* H       = (const float*)d_in[0];
    // d_in[1] = batch (implied by n/125, unused)
    const int*   targets = (const int*)d_in[2];
    const float* w1      = (const float*)d_in[3];
    const float* b1      = (const float*)d_in[4];
    const float* w2      = (const float*)d_in[5];
    const float* b2      = (const float*)d_in[6];
    const float* wf      = (const float*)d_in[7];
    const float* bf      = (const float*)d_in[8];
    const float* p1      = (const float*)d_in[9];
    const float* pb1     = (const float*)d_in[10];
    const float* p2      = (const float*)d_in[11];
    const float* pb2     = (const float*)d_in[12];
    const float* ci      = (const float*)d_in[13];
    const float* cr      = (const float*)d_in[14];

    float* out   = (float*)d_out;
    float* pred1 = out + OFF_PRED1;
    float* pred2 = out + OFF_PRED2;
    float* ind   = out + OFF_IND;
    float* S     = out + OFF_S;
    float* E     = out + OFF_E;
    float* Q     = out + OFF_Q;

    short* ws = (short*)d_ws;   // 40960 B of pre-split w1 fragments

    k_split_w1<<<40, 256, 0, stream>>>(w1, ws);
    k_fused<<<NG, 256, 0, stream>>>(H, ws, b1, w2, b2, wf, bf, targets,
                                    p1, pb1, p2, pb2, ci, cr,
                                    S, E, pred1, pred2, ind, Q);
}